// Round 1
// baseline (797.854 us; speedup 1.0000x reference)
//
#include <hip/hip_runtime.h>
#include <hip/hip_bf16.h>
#include <stdint.h>

#define NTOK 4096
#define DDIM 1024
#define HDIM 4096
#define ODIM 1024
#define NEXP 8
#define BM 128
#define BN 128
#define BK 64
#define CAPROWS (NTOK * 2 + NEXP * BM) /* 9216 padded rows worst case */
#define MAXTILES (CAPROWS / BM)        /* 72 */

typedef float f32x4_t __attribute__((ext_vector_type(4)));
typedef short bf16x8_t __attribute__((ext_vector_type(8)));
using bf16_t = __hip_bfloat16;

__device__ __forceinline__ void gll16(const void* g, void* l) {
  __builtin_amdgcn_global_load_lds(
      (__attribute__((address_space(1))) void*)(void*)g,
      (__attribute__((address_space(3))) void*)l, 16, 0, 0);
}

// ---------------- gate: logits + softmax + top2 (all fp32, exact) -----------
__global__ __launch_bounds__(256) void gate_kernel(
    const float* __restrict__ x, const float* __restrict__ gw,
    const float* __restrict__ gb, int* __restrict__ top_idx,
    float* __restrict__ top_val, int* __restrict__ counts) {
  int n = blockIdx.x * 4 + (threadIdx.x >> 6);
  int l = threadIdx.x & 63;
  const float4* xv = (const float4*)(x + (size_t)n * DDIM);
  float4 xs[4];
#pragma unroll
  for (int j = 0; j < 4; ++j) xs[j] = xv[l + 64 * j];
  float part[NEXP];
#pragma unroll
  for (int e = 0; e < NEXP; ++e) {
    const float4* wv = (const float4*)(gw + (size_t)e * DDIM);
    float s = 0.f;
#pragma unroll
    for (int j = 0; j < 4; ++j) {
      float4 w4 = wv[l + 64 * j];
      s += xs[j].x * w4.x + xs[j].y * w4.y + xs[j].z * w4.z + xs[j].w * w4.w;
    }
    part[e] = s;
  }
#pragma unroll
  for (int off = 32; off > 0; off >>= 1)
#pragma unroll
    for (int e = 0; e < NEXP; ++e) part[e] += __shfl_xor(part[e], off, 64);

  float m = -1e30f;
#pragma unroll
  for (int e = 0; e < NEXP; ++e) { part[e] += gb[e]; m = fmaxf(m, part[e]); }
  float ssum = 0.f;
#pragma unroll
  for (int e = 0; e < NEXP; ++e) { part[e] = expf(part[e] - m); ssum += part[e]; }
  int i0 = 0; float v0 = part[0];
#pragma unroll
  for (int e = 1; e < NEXP; ++e) if (part[e] > v0) { v0 = part[e]; i0 = e; }
  int i1 = -1; float v1 = -1e30f;
#pragma unroll
  for (int e = 0; e < NEXP; ++e) if (e != i0 && part[e] > v1) { v1 = part[e]; i1 = e; }
  if (l == 0) {
    float inv = 1.f / ssum;
    top_idx[n * 2] = i0; top_idx[n * 2 + 1] = i1;
    top_val[n * 2] = v0 * inv; top_val[n * 2 + 1] = v1 * inv;
    atomicAdd(&counts[i0], 1); atomicAdd(&counts[i1], 1);
  }
}

// ---------------- plan: padded prefix offsets + static tile table -----------
__global__ void plan_kernel(const int* __restrict__ counts, int* __restrict__ offs,
                            int* __restrict__ tile_e, int* __restrict__ tile_r) {
  if (threadIdx.x != 0 || blockIdx.x != 0) return;
  int off = 0, t = 0;
  for (int e = 0; e < NEXP; ++e) {
    offs[e] = off;
    int padded = ((counts[e] + BM - 1) / BM) * BM;
    for (int r = 0; r < padded; r += BM) { tile_e[t] = e; tile_r[t] = off + r; ++t; }
    off += padded;
  }
  offs[NEXP] = off;
  for (; t < MAXTILES; ++t) { tile_e[t] = -1; tile_r[t] = 0; }
}

// ---------------- gather: token rows -> per-expert bf16 blocks --------------
__global__ __launch_bounds__(128) void gather_kernel(
    const float* __restrict__ x, const int* __restrict__ top_idx,
    const int* __restrict__ offs, int* __restrict__ cursors,
    int* __restrict__ slot_for, bf16_t* __restrict__ Xg) {
  int a = blockIdx.x;
  __shared__ int s_slot;
  if (threadIdx.x == 0) {
    int e = top_idx[a];
    int pos = atomicAdd(&cursors[e], 1);
    int slot = offs[e] + pos;
    slot_for[a] = slot;
    s_slot = slot;
  }
  __syncthreads();
  int slot = s_slot;
  int n = a >> 1;
  const float4* xv = (const float4*)(x + (size_t)n * DDIM);
  float4 a0 = xv[threadIdx.x * 2], a1 = xv[threadIdx.x * 2 + 1];
  __align__(16) bf16_t tmp[8] = {
      __float2bfloat16(a0.x), __float2bfloat16(a0.y),
      __float2bfloat16(a0.z), __float2bfloat16(a0.w),
      __float2bfloat16(a1.x), __float2bfloat16(a1.y),
      __float2bfloat16(a1.z), __float2bfloat16(a1.w)};
  *(uint4*)(Xg + (size_t)slot * DDIM + threadIdx.x * 8) = *(const uint4*)tmp;
}

// ---------------- transpose-convert fp32 [E][R][C] -> bf16 [E][C][R] --------
__global__ __launch_bounds__(256) void convT_kernel(
    const float* __restrict__ src, bf16_t* __restrict__ dst, int R, int C) {
  __shared__ float tile[64][65];
  int e = blockIdx.z;
  int c0 = blockIdx.x * 64, r0 = blockIdx.y * 64;
  const float* s = src + ((size_t)e * R + r0) * C + c0;
  int tc = threadIdx.x & 63, tr = threadIdx.x >> 6;
#pragma unroll
  for (int p = 0; p < 16; ++p) {
    int r = tr + p * 4;
    tile[r][tc] = s[(size_t)r * C + tc];
  }
  __syncthreads();
  bf16_t* d = dst + ((size_t)e * C + c0) * R + r0;
  int oc = threadIdx.x >> 2;
  int orq = (threadIdx.x & 3) * 16;
#pragma unroll
  for (int j = 0; j < 4; ++j) {
    __align__(8) bf16_t v[4];
#pragma unroll
    for (int i = 0; i < 4; ++i) v[i] = __float2bfloat16(tile[orq + j * 4 + i][oc]);
    *(uint2*)(d + (size_t)oc * R + orq + j * 4) = *(const uint2*)v;
  }
}

// ---------------- MFMA GEMM: C = A[M][K] @ Bt[N][K]^T, tiles from table -----
// A row-major bf16, Bt row-major (pre-transposed) bf16.
// WHICH==1: relu(acc+bias) -> bf16 out. WHICH==2: acc+bias -> f32 out.
// LDS XOR-swizzle (T2, rule #21): linear global_load_lds dest, inverse-swizzled
// global source, swizzled ds_read -> conflict-free ds_read_b128.
template <int KTOT, int NTOT, int WHICH>
__global__ __launch_bounds__(256, 2) void gemm_kernel(
    const bf16_t* __restrict__ A, const bf16_t* __restrict__ Bt,
    const float* __restrict__ bias, void* __restrict__ Cout,
    const int* __restrict__ tile_e, const int* __restrict__ tile_r) {
  int e = tile_e[blockIdx.y];
  if (e < 0) return;
  int row0 = tile_r[blockIdx.y];
  int n0 = blockIdx.x * BN;
  int tid = threadIdx.x;

  __shared__ bf16_t As[2][BM * BK];
  __shared__ bf16_t Bs[2][BN * BK];

  const bf16_t* Ab = A + (size_t)row0 * KTOT;
  const bf16_t* Bb = Bt + ((size_t)e * NTOT + n0) * KTOT;

  int l = tid & 63;
  int w = tid >> 6;
  int wr = (w >> 1) * 64;
  int wc = (w & 1) * 64;
  int lrow = l & 15, lk = l >> 4;

  // staging: thread t covers LDS bytes (it*256+t)*16; row = it*32 + (t>>3),
  // physical chunk = t&7 holds logical chunk (t&7)^(row&7).
  int st_row = tid >> 3;
  int st_lc = (tid & 7) ^ (st_row & 7);

  // fragment read byte-offsets (swizzled): row*128 + ((ks*4+lk)^(l&7))*16
  int aoff[2][4], boff[2][4];
#pragma unroll
  for (int ks = 0; ks < 2; ++ks) {
    int pc = (ks * 4 + lk) ^ (l & 7);
#pragma unroll
    for (int f = 0; f < 4; ++f) {
      aoff[ks][f] = ((wr + f * 16 + lrow) * BK) * 2 + pc * 16;
      boff[ks][f] = ((wc + f * 16 + lrow) * BK) * 2 + pc * 16;
    }
  }

  f32x4_t acc[4][4];
#pragma unroll
  for (int i = 0; i < 4; ++i)
#pragma unroll
    for (int j = 0; j < 4; ++j) acc[i][j] = (f32x4_t){0.f, 0.f, 0.f, 0.f};

  const int NKT = KTOT / BK;

#pragma unroll
  for (int it = 0; it < 4; ++it) {
    int r = st_row + it * 32;
    gll16(Ab + (size_t)r * KTOT + st_lc * 8, (char*)As[0] + (it * 256 + tid) * 16);
    gll16(Bb + (size_t)r * KTOT + st_lc * 8, (char*)Bs[0] + (it * 256 + tid) * 16);
  }
  __syncthreads();

  int cur = 0;
  for (int kt = 0; kt < NKT; ++kt) {
    if (kt + 1 < NKT) {
      int kb = (kt + 1) * BK + st_lc * 8;
#pragma unroll
      for (int it = 0; it < 4; ++it) {
        int r = st_row + it * 32;
        gll16(Ab + (size_t)r * KTOT + kb, (char*)As[cur ^ 1] + (it * 256 + tid) * 16);
        gll16(Bb + (size_t)r * KTOT + kb, (char*)Bs[cur ^ 1] + (it * 256 + tid) * 16);
      }
    }
#pragma unroll
    for (int ks = 0; ks < 2; ++ks) {
      bf16x8_t av[4], bv[4];
#pragma unroll
      for (int f = 0; f < 4; ++f)
        av[f] = *(const bf16x8_t*)((const char*)As[cur] + aoff[ks][f]);
#pragma unroll
      for (int f = 0; f < 4; ++f)
        bv[f] = *(const bf16x8_t*)((const char*)Bs[cur] + boff[ks][f]);
#pragma unroll
      for (int fm = 0; fm < 4; ++fm)
#pragma unroll
        for (int fn = 0; fn < 4; ++fn)
          acc[fm][fn] = __builtin_amdgcn_mfma_f32_16x16x32_bf16(
              av[fm], bv[fn], acc[fm][fn], 0, 0, 0);
    }
    __syncthreads();
    cur ^= 1;
  }

  // epilogue: C/D layout col=lane&15, row=(lane>>4)*4+i  [m89-verified]
#pragma unroll
  for (int fn = 0; fn < 4; ++fn) {
    int col = n0 + wc + fn * 16 + lrow;
    float bv = bias[e * NTOT + col];
#pragma unroll
    for (int fm = 0; fm < 4; ++fm) {
      size_t rbase = (size_t)row0 + wr + fm * 16 + lk * 4;
#pragma unroll
      for (int i = 0; i < 4; ++i) {
        float v = acc[fm][fn][i] + bv;
        if (WHICH == 1) {
          v = v > 0.f ? v : 0.f;
          ((bf16_t*)Cout)[(rbase + i) * NTOT + col] = __float2bfloat16(v);
        } else {
          ((float*)Cout)[(rbase + i) * NTOT + col] = v;
        }
      }
    }
  }
}

// ---------------- combine: out[n] = g0*Y[s0] + g1*Y[s1] ---------------------
__global__ __launch_bounds__(256) void combine_kernel(
    const float* __restrict__ Y, const int* __restrict__ slot_for,
    const float* __restrict__ top_val, float* __restrict__ out) {
  int n = blockIdx.x;
  int s0 = slot_for[n * 2], s1 = slot_for[n * 2 + 1];
  float v0 = top_val[n * 2], v1 = top_val[n * 2 + 1];
  int t = threadIdx.x;
  float4 a = ((const float4*)(Y + (size_t)s0 * ODIM))[t];
  float4 b = ((const float4*)(Y + (size_t)s1 * ODIM))[t];
  float4 r;
  r.x = v0 * a.x + v1 * b.x;
  r.y = v0 * a.y + v1 * b.y;
  r.z = v0 * a.z + v1 * b.z;
  r.w = v0 * a.w + v1 * b.w;
  ((float4*)(out + (size_t)n * ODIM))[t] = r;
}

__global__ void zero_meta_kernel(int* p) {
  if (threadIdx.x < 16) p[threadIdx.x] = 0;
}

extern "C" void kernel_launch(void* const* d_in, const int* in_sizes, int n_in,
                              void* d_out, int out_size, void* d_ws, size_t ws_size,
                              hipStream_t stream) {
  const float* x  = (const float*)d_in[0];
  const float* gw = (const float*)d_in[1];
  const float* gb = (const float*)d_in[2];
  const float* w1 = (const float*)d_in[3];
  const float* b1 = (const float*)d_in[4];
  const float* w2 = (const float*)d_in[5];
  const float* b2 = (const float*)d_in[6];
  float* out = (float*)d_out;

  char* ws = (char*)d_ws;
  size_t off = 0;
  auto alloc = [&](size_t bytes) {
    void* p = ws + off;
    off = (off + bytes + 255) & ~(size_t)255;
    return p;
  };
  bf16_t* w1T = (bf16_t*)alloc((size_t)NEXP * HDIM * DDIM * 2);  // 67.1 MB
  bf16_t* w2T = (bf16_t*)alloc((size_t)NEXP * ODIM * HDIM * 2);  // 67.1 MB
  bf16_t* Xg  = (bf16_t*)alloc((size_t)CAPROWS * DDIM * 2);      // 18.9 MB
  bf16_t* Hb  = (bf16_t*)alloc((size_t)CAPROWS * HDIM * 2);      // 75.5 MB
  int* counts  = (int*)alloc(64);  // counts[8] + cursors[8]
  int* cursors = counts + 8;
  int* offs    = (int*)alloc(64);
  int* tile_e  = (int*)alloc(MAXTILES * 4);
  int* tile_r  = (int*)alloc(MAXTILES * 4);
  int* top_idx = (int*)alloc((size_t)NTOK * 2 * 4);
  float* top_val = (float*)alloc((size_t)NTOK * 2 * 4);
  int* slot_for = (int*)alloc((size_t)NTOK * 2 * 4);
  // GEMM2 output overlays w1T (dead after GEMM1): 37.7 MB <= 67.1 MB
  float* Yb = (float*)w1T;

  hipLaunchKernelGGL(zero_meta_kernel, dim3(1), dim3(64), 0, stream, counts);
  hipMemsetAsync(Xg, 0, (size_t)CAPROWS * DDIM * 2, stream);
  hipLaunchKernelGGL(convT_kernel, dim3(HDIM / 64, DDIM / 64, NEXP), dim3(256), 0,
                     stream, w1, w1T, DDIM, HDIM);
  hipLaunchKernelGGL(convT_kernel, dim3(ODIM / 64, HDIM / 64, NEXP), dim3(256), 0,
                     stream, w2, w2T, HDIM, ODIM);
  hipLaunchKernelGGL(gate_kernel, dim3(NTOK / 4), dim3(256), 0, stream,
                     x, gw, gb, top_idx, top_val, counts);
  hipLaunchKernelGGL(plan_kernel, dim3(1), dim3(1), 0, stream,
                     counts, offs, tile_e, tile_r);
  hipLaunchKernelGGL(gather_kernel, dim3(NTOK * 2), dim3(128), 0, stream,
                     x, top_idx, offs, cursors, slot_for, Xg);
  hipLaunchKernelGGL((gemm_kernel<DDIM, HDIM, 1>), dim3(HDIM / BN, MAXTILES),
                     dim3(256), 0, stream, Xg, w1T, b1, Hb, tile_e, tile_r);
  hipLaunchKernelGGL((gemm_kernel<HDIM, ODIM, 2>), dim3(ODIM / BN, MAXTILES),
                     dim3(256), 0, stream, Hb, w2T, b2, Yb, tile_e, tile_r);
  hipLaunchKernelGGL(combine_kernel, dim3(NTOK), dim3(256), 0, stream,
                     Yb, slot_for, top_val, out);
}

// Round 2
// 736.210 us; speedup vs baseline: 1.0837x; 1.0837x over previous
//
#include <hip/hip_runtime.h>
#include <hip/hip_bf16.h>
#include <stdint.h>

#define NTOK 4096
#define DDIM 1024
#define HDIM 4096
#define ODIM 1024
#define NEXP 8
#define BM 256
#define BN 256
#define BK 64
#define CAPROWS (NTOK * 2 + NEXP * BM) /* 10240 padded rows worst case */
#define MAXTILES (CAPROWS / BM)        /* 40 */

typedef float f32x4_t __attribute__((ext_vector_type(4)));
typedef short bf16x8_t __attribute__((ext_vector_type(8)));
using bf16_t = __hip_bfloat16;

#define S_BARRIER()                         \
  do {                                      \
    __builtin_amdgcn_sched_barrier(0);      \
    __builtin_amdgcn_s_barrier();           \
    __builtin_amdgcn_sched_barrier(0);      \
  } while (0)
#define WAIT_LGKM0()                                  \
  do {                                                \
    asm volatile("s_waitcnt lgkmcnt(0)" ::: "memory");\
    __builtin_amdgcn_sched_barrier(0);                \
  } while (0)
#define WAIT_VMCNT(n)                                       \
  do {                                                      \
    asm volatile("s_waitcnt vmcnt(" #n ")" ::: "memory");   \
    __builtin_amdgcn_sched_barrier(0);                      \
  } while (0)

__device__ __forceinline__ void gll16(const void* g, void* l) {
  __builtin_amdgcn_global_load_lds(
      (__attribute__((address_space(1))) void*)(void*)g,
      (__attribute__((address_space(3))) void*)l, 16, 0, 0);
}

// ---------------- gate: logits + softmax + top2 (all fp32, exact) -----------
__global__ __launch_bounds__(256) void gate_kernel(
    const float* __restrict__ x, const float* __restrict__ gw,
    const float* __restrict__ gb, int* __restrict__ top_idx,
    float* __restrict__ top_val, int* __restrict__ counts) {
  int n = blockIdx.x * 4 + (threadIdx.x >> 6);
  int l = threadIdx.x & 63;
  const float4* xv = (const float4*)(x + (size_t)n * DDIM);
  float4 xs[4];
#pragma unroll
  for (int j = 0; j < 4; ++j) xs[j] = xv[l + 64 * j];
  float part[NEXP];
#pragma unroll
  for (int e = 0; e < NEXP; ++e) {
    const float4* wv = (const float4*)(gw + (size_t)e * DDIM);
    float s = 0.f;
#pragma unroll
    for (int j = 0; j < 4; ++j) {
      float4 w4 = wv[l + 64 * j];
      s += xs[j].x * w4.x + xs[j].y * w4.y + xs[j].z * w4.z + xs[j].w * w4.w;
    }
    part[e] = s;
  }
#pragma unroll
  for (int off = 32; off > 0; off >>= 1)
#pragma unroll
    for (int e = 0; e < NEXP; ++e) part[e] += __shfl_xor(part[e], off, 64);

  float m = -1e30f;
#pragma unroll
  for (int e = 0; e < NEXP; ++e) { part[e] += gb[e]; m = fmaxf(m, part[e]); }
  float ssum = 0.f;
#pragma unroll
  for (int e = 0; e < NEXP; ++e) { part[e] = expf(part[e] - m); ssum += part[e]; }
  int i0 = 0; float v0 = part[0];
#pragma unroll
  for (int e = 1; e < NEXP; ++e) if (part[e] > v0) { v0 = part[e]; i0 = e; }
  int i1 = -1; float v1 = -1e30f;
#pragma unroll
  for (int e = 0; e < NEXP; ++e) if (e != i0 && part[e] > v1) { v1 = part[e]; i1 = e; }
  if (l == 0) {
    float inv = 1.f / ssum;
    top_idx[n * 2] = i0; top_idx[n * 2 + 1] = i1;
    top_val[n * 2] = v0 * inv; top_val[n * 2 + 1] = v1 * inv;
    atomicAdd(&counts[i0], 1); atomicAdd(&counts[i1], 1);
  }
}

// ---------------- plan: padded prefix offsets + static tile table -----------
__global__ void plan_kernel(const int* __restrict__ counts, int* __restrict__ offs,
                            int* __restrict__ tile_e, int* __restrict__ tile_r) {
  if (threadIdx.x != 0 || blockIdx.x != 0) return;
  int off = 0, t = 0;
  for (int e = 0; e < NEXP; ++e) {
    offs[e] = off;
    int padded = ((counts[e] + BM - 1) / BM) * BM;
    for (int r = 0; r < padded; r += BM) { tile_e[t] = e; tile_r[t] = off + r; ++t; }
    off += padded;
  }
  offs[NEXP] = off;
  for (; t < MAXTILES; ++t) { tile_e[t] = -1; tile_r[t] = 0; }
}

// ---------------- gather: token rows -> per-expert bf16 blocks --------------
__global__ __launch_bounds__(128) void gather_kernel(
    const float* __restrict__ x, const int* __restrict__ top_idx,
    const int* __restrict__ offs, int* __restrict__ cursors,
    int* __restrict__ slot_for, bf16_t* __restrict__ Xg) {
  int a = blockIdx.x;
  __shared__ int s_slot;
  if (threadIdx.x == 0) {
    int e = top_idx[a];
    int pos = atomicAdd(&cursors[e], 1);
    int slot = offs[e] + pos;
    slot_for[a] = slot;
    s_slot = slot;
  }
  __syncthreads();
  int slot = s_slot;
  int n = a >> 1;
  const float4* xv = (const float4*)(x + (size_t)n * DDIM);
  float4 a0 = xv[threadIdx.x * 2], a1 = xv[threadIdx.x * 2 + 1];
  __align__(16) bf16_t tmp[8] = {
      __float2bfloat16(a0.x), __float2bfloat16(a0.y),
      __float2bfloat16(a0.z), __float2bfloat16(a0.w),
      __float2bfloat16(a1.x), __float2bfloat16(a1.y),
      __float2bfloat16(a1.z), __float2bfloat16(a1.w)};
  *(uint4*)(Xg + (size_t)slot * DDIM + threadIdx.x * 8) = *(const uint4*)tmp;
}

// ---------------- transpose-convert fp32 [E][R][C] -> bf16 [E][C][R] --------
// Coalesced writes: 8 threads cover 64 consecutive rows of one column
// (8x uint4 = 128B contiguous run per column).
__global__ __launch_bounds__(256) void convT_kernel(
    const float* __restrict__ src, bf16_t* __restrict__ dst, int R, int C) {
  __shared__ float tile[64][65];
  int e = blockIdx.z;
  int c0 = blockIdx.x * 64, r0 = blockIdx.y * 64;
  const float* s = src + ((size_t)e * R + r0) * C + c0;
  int tc = threadIdx.x & 63, tr = threadIdx.x >> 6;
#pragma unroll
  for (int p = 0; p < 16; ++p) {
    int r = tr + p * 4;
    tile[r][tc] = s[(size_t)r * C + tc];
  }
  __syncthreads();
  bf16_t* dcol = dst + ((size_t)e * C + c0) * R + r0;
  int t = threadIdx.x;
#pragma unroll
  for (int it = 0; it < 2; ++it) {
    int c = (t >> 3) + it * 32;
    int r8 = (t & 7) * 8;
    __align__(16) bf16_t v[8];
#pragma unroll
    for (int j = 0; j < 8; ++j) v[j] = __float2bfloat16(tile[r8 + j][c]);
    *(uint4*)(dcol + (size_t)c * R + r8) = *(const uint4*)v;
  }
}

// ---------------- 256x256 8-phase MFMA GEMM (T2+T3+T4+T5) -------------------
// C = A[M][K] @ Bt[N][K]^T  per expert-tile. A row-major bf16, Bt row-major.
// 512 threads = 8 waves (2M x 4N); per-wave 128x64 output; BK=64, 2 LDS dbufs.
// LDS 128KB: A 2x[256][64], B 2x[256][64], XOR-swizzled slots (slot ^= row&7)
// via pre-swizzled global source (linear gll16 dest) + swizzled ds_read.
// Schedule per K-tile t (dbuf d=t&1):
//   ph0: read a[ks0](8)+b[ks0](4); stage B-h0(t+1)->d^1 | BAR lgkm0 prio MFMA(m0-3,ks0) BAR
//   ph1: read a[ks1](8);           stage B-h1(t+1)->d^1 | BAR lgkm0 prio MFMA(m4-7,ks0) BAR
//   ph2: read b[ks1](4);           stage A-h0(t+2)->d   | BAR lgkm0 prio MFMA(m0-3,ks1) BAR
//   ph3:                           stage A-h1(t+2)->d; vmcnt(4) | BAR prio MFMA(m4-7,ks1) BAR
// Region safety: A(d) reads drained by ph1's lgkm0 -> overwrite at ph2+ ok;
// B(d^1) free since t-1. vmcnt(4) = 2 half-tiles (A(t+2)) allowed in flight.
template <int KTOT, int NTOT, int WHICH>
__global__ __launch_bounds__(512, 2) void gemm8_kernel(
    const bf16_t* __restrict__ A, const bf16_t* __restrict__ Bt,
    const float* __restrict__ bias, void* __restrict__ Cout,
    const int* __restrict__ tile_e, const int* __restrict__ tile_r) {
  constexpr int NCOL = NTOT / BN;
  // bijective XCD-chunked swizzle (m204)
  int nwg = gridDim.x;
  int bid = blockIdx.x;
  int q = nwg >> 3, rr = nwg & 7;
  int xcd = bid & 7, pos = bid >> 3;
  int swz = (xcd < rr ? xcd * (q + 1) : rr * (q + 1) + (xcd - rr) * q) + pos;
  int ty = swz / NCOL, tx = swz % NCOL;

  int e = tile_e[ty];
  if (e < 0) return;
  int row0 = tile_r[ty];
  int n0 = tx * BN;

  __shared__ char smem[131072];
  int tid = threadIdx.x;
  int w = tid >> 6, l = tid & 63;
  int wm = w >> 2, wn = w & 3;
  int lrow = l & 15, lk = l >> 4;

  const bf16_t* Ab = A + (size_t)row0 * KTOT;
  const bf16_t* Bb = Bt + ((size_t)e * NTOT + n0) * KTOT;

  // staging map: load wv in {0,1}: idx = wv*512+tid; r=idx>>3, s=idx&7;
  // source col-slot = s ^ (r&7); LDS dest linear idx*16.
  int sidx0 = tid, sidx1 = 512 + tid;
  int sr0 = sidx0 >> 3, sc0 = (sidx0 & 7) ^ (sr0 & 7);
  int sr1 = sidx1 >> 3, sc1 = (sidx1 & 7) ^ (sr1 & 7);

  auto stageA = [&](int kt, int h, int d) {
    char* lb = smem + d * 32768 + h * 16384;
    const bf16_t* g = Ab + (size_t)(h * 128) * KTOT + kt * BK;
    gll16(g + (size_t)sr0 * KTOT + sc0 * 8, lb + sidx0 * 16);
    gll16(g + (size_t)sr1 * KTOT + sc1 * 8, lb + sidx1 * 16);
  };
  auto stageB = [&](int kt, int h, int d) {
    char* lb = smem + 65536 + d * 32768 + h * 16384;
    const bf16_t* g = Bb + (size_t)(h * 128) * KTOT + kt * BK;
    gll16(g + (size_t)sr0 * KTOT + sc0 * 8, lb + sidx0 * 16);
    gll16(g + (size_t)sr1 * KTOT + sc1 * 8, lb + sidx1 * 16);
  };

  // fragment read byte offsets: row r -> r*128 + ((ks*4+lk)^(r&7))*16,
  // r&7 == lrow&7 for all frags.
  int abase = (wm * 128 + lrow) * 128;
  int bbase = (wn * 64 + lrow) * 128;
  int p0 = ((lk) ^ (lrow & 7)) * 16;
  int p1 = ((4 + lk) ^ (lrow & 7)) * 16;

  f32x4_t acc[8][4];
#pragma unroll
  for (int m = 0; m < 8; ++m)
#pragma unroll
    for (int n = 0; n < 4; ++n) acc[m][n] = (f32x4_t){0.f, 0.f, 0.f, 0.f};

  const int NKT = KTOT / BK;

  // prologue: A(0), B(0), A(1)
  stageA(0, 0, 0); stageA(0, 1, 0);
  stageB(0, 0, 0); stageB(0, 1, 0);
  stageA(1, 0, 1); stageA(1, 1, 1);
  WAIT_VMCNT(4);
  S_BARRIER();

  for (int t = 0; t < NKT; ++t) {
    int d = t & 1;
    const char* Ad = smem + d * 32768;
    const char* Bd = smem + 65536 + d * 32768;
    bf16x8_t ak0[8], ak1[8], bv[4];
    // ---- ph0 ----
#pragma unroll
    for (int m = 0; m < 8; ++m)
      ak0[m] = *(const bf16x8_t*)(Ad + abase + m * 2048 + p0);
#pragma unroll
    for (int n = 0; n < 4; ++n)
      bv[n] = *(const bf16x8_t*)(Bd + bbase + n * 2048 + p0);
    if (t + 1 < NKT) stageB(t + 1, 0, d ^ 1);
    S_BARRIER();
    WAIT_LGKM0();
    __builtin_amdgcn_s_setprio(1);
#pragma unroll
    for (int m = 0; m < 4; ++m)
#pragma unroll
      for (int n = 0; n < 4; ++n)
        acc[m][n] = __builtin_amdgcn_mfma_f32_16x16x32_bf16(ak0[m], bv[n], acc[m][n], 0, 0, 0);
    __builtin_amdgcn_s_setprio(0);
    S_BARRIER();
    // ---- ph1 ----
#pragma unroll
    for (int m = 0; m < 8; ++m)
      ak1[m] = *(const bf16x8_t*)(Ad + abase + m * 2048 + p1);
    if (t + 1 < NKT) stageB(t + 1, 1, d ^ 1);
    S_BARRIER();
    WAIT_LGKM0();
    __builtin_amdgcn_s_setprio(1);
#pragma unroll
    for (int m = 4; m < 8; ++m)
#pragma unroll
      for (int n = 0; n < 4; ++n)
        acc[m][n] = __builtin_amdgcn_mfma_f32_16x16x32_bf16(ak0[m], bv[n], acc[m][n], 0, 0, 0);
    __builtin_amdgcn_s_setprio(0);
    S_BARRIER();
    // ---- ph2 ----
#pragma unroll
    for (int n = 0; n < 4; ++n)
      bv[n] = *(const bf16x8_t*)(Bd + bbase + n * 2048 + p1);
    if (t + 2 < NKT) stageA(t + 2, 0, d);
    S_BARRIER();
    WAIT_LGKM0();
    __builtin_amdgcn_s_setprio(1);
#pragma unroll
    for (int m = 0; m < 4; ++m)
#pragma unroll
      for (int n = 0; n < 4; ++n)
        acc[m][n] = __builtin_amdgcn_mfma_f32_16x16x32_bf16(ak1[m], bv[n], acc[m][n], 0, 0, 0);
    __builtin_amdgcn_s_setprio(0);
    S_BARRIER();
    // ---- ph3 ----
    if (t + 2 < NKT) {
      stageA(t + 2, 1, d);
      WAIT_VMCNT(4);
    } else {
      WAIT_VMCNT(0);
    }
    S_BARRIER();
    __builtin_amdgcn_s_setprio(1);
#pragma unroll
    for (int m = 4; m < 8; ++m)
#pragma unroll
      for (int n = 0; n < 4; ++n)
        acc[m][n] = __builtin_amdgcn_mfma_f32_16x16x32_bf16(ak1[m], bv[n], acc[m][n], 0, 0, 0);
    __builtin_amdgcn_s_setprio(0);
    S_BARRIER();
  }

  // epilogue: C/D layout col=lane&15, row=(lane>>4)*4+i [m89-verified]
#pragma unroll
  for (int n = 0; n < 4; ++n) {
    int col = n0 + wn * 64 + n * 16 + lrow;
    float bb = bias[e * NTOT + col];
#pragma unroll
    for (int m = 0; m < 8; ++m) {
      size_t rb = (size_t)row0 + wm * 128 + m * 16 + lk * 4;
#pragma unroll
      for (int i = 0; i < 4; ++i) {
        float v = acc[m][n][i] + bb;
        if (WHICH == 1) {
          v = v > 0.f ? v : 0.f;
          ((bf16_t*)Cout)[(rb + i) * NTOT + col] = __float2bfloat16(v);
        } else {
          ((float*)Cout)[(rb + i) * NTOT + col] = v;
        }
      }
    }
  }
}

// ---------------- combine: out[n] = g0*Y[s0] + g1*Y[s1] ---------------------
__global__ __launch_bounds__(256) void combine_kernel(
    const float* __restrict__ Y, const int* __restrict__ slot_for,
    const float* __restrict__ top_val, float* __restrict__ out) {
  int n = blockIdx.x;
  int s0 = slot_for[n * 2], s1 = slot_for[n * 2 + 1];
  float v0 = top_val[n * 2], v1 = top_val[n * 2 + 1];
  int t = threadIdx.x;
  float4 a = ((const float4*)(Y + (size_t)s0 * ODIM))[t];
  float4 b = ((const float4*)(Y + (size_t)s1 * ODIM))[t];
  float4 r;
  r.x = v0 * a.x + v1 * b.x;
  r.y = v0 * a.y + v1 * b.y;
  r.z = v0 * a.z + v1 * b.z;
  r.w = v0 * a.w + v1 * b.w;
  ((float4*)(out + (size_t)n * ODIM))[t] = r;
}

__global__ void zero_meta_kernel(int* p) {
  if (threadIdx.x < 16) p[threadIdx.x] = 0;
}

extern "C" void kernel_launch(void* const* d_in, const int* in_sizes, int n_in,
                              void* d_out, int out_size, void* d_ws, size_t ws_size,
                              hipStream_t stream) {
  const float* x  = (const float*)d_in[0];
  const float* gw = (const float*)d_in[1];
  const float* gb = (const float*)d_in[2];
  const float* w1 = (const float*)d_in[3];
  const float* b1 = (const float*)d_in[4];
  const float* w2 = (const float*)d_in[5];
  const float* b2 = (const float*)d_in[6];
  float* out = (float*)d_out;

  char* ws = (char*)d_ws;
  size_t off = 0;
  auto alloc = [&](size_t bytes) {
    void* p = ws + off;
    off = (off + bytes + 255) & ~(size_t)255;
    return p;
  };
  bf16_t* w1T = (bf16_t*)alloc((size_t)NEXP * HDIM * DDIM * 2);  // 67.1 MB
  bf16_t* w2T = (bf16_t*)alloc((size_t)NEXP * ODIM * HDIM * 2);  // 67.1 MB
  bf16_t* Xg  = (bf16_t*)alloc((size_t)CAPROWS * DDIM * 2);      // 21.0 MB
  bf16_t* Hb  = (bf16_t*)alloc((size_t)CAPROWS * HDIM * 2);      // 83.9 MB
  int* counts  = (int*)alloc(64);  // counts[8] + cursors[8]
  int* cursors = counts + 8;
  int* offs    = (int*)alloc(64);
  int* tile_e  = (int*)alloc(MAXTILES * 4);
  int* tile_r  = (int*)alloc(MAXTILES * 4);
  int* top_idx = (int*)alloc((size_t)NTOK * 2 * 4);
  float* top_val = (float*)alloc((size_t)NTOK * 2 * 4);
  int* slot_for = (int*)alloc((size_t)NTOK * 2 * 4);
  // GEMM2 output overlays w1T (dead after GEMM1): 41.9 MB <= 67.1 MB
  float* Yb = (float*)w1T;

  hipLaunchKernelGGL(zero_meta_kernel, dim3(1), dim3(64), 0, stream, counts);
  hipMemsetAsync(Xg, 0, (size_t)CAPROWS * DDIM * 2, stream);
  hipLaunchKernelGGL(convT_kernel, dim3(HDIM / 64, DDIM / 64, NEXP), dim3(256), 0,
                     stream, w1, w1T, DDIM, HDIM);
  hipLaunchKernelGGL(convT_kernel, dim3(ODIM / 64, HDIM / 64, NEXP), dim3(256), 0,
                     stream, w2, w2T, HDIM, ODIM);
  hipLaunchKernelGGL(gate_kernel, dim3(NTOK / 4), dim3(256), 0, stream,
                     x, gw, gb, top_idx, top_val, counts);
  hipLaunchKernelGGL(plan_kernel, dim3(1), dim3(1), 0, stream,
                     counts, offs, tile_e, tile_r);
  hipLaunchKernelGGL(gather_kernel, dim3(NTOK * 2), dim3(128), 0, stream,
                     x, top_idx, offs, cursors, slot_for, Xg);
  hipLaunchKernelGGL((gemm8_kernel<DDIM, HDIM, 1>),
                     dim3((HDIM / BN) * MAXTILES), dim3(512), 0, stream,
                     Xg, w1T, b1, Hb, tile_e, tile_r);
  hipLaunchKernelGGL((gemm8_kernel<HDIM, ODIM, 2>),
                     dim3((ODIM / BN) * MAXTILES), dim3(512), 0, stream,
                     Hb, w2T, b2, Yb, tile_e, tile_r);
  hipLaunchKernelGGL(combine_kernel, dim3(NTOK), dim3(256), 0, stream,
                     Yb, slot_for, top_val, out);
}

// Round 3
// 735.965 us; speedup vs baseline: 1.0841x; 1.0003x over previous
//
#include <hip/hip_runtime.h>
#include <hip/hip_bf16.h>
#include <stdint.h>

#define NTOK 4096
#define DDIM 1024
#define HDIM 4096
#define ODIM 1024
#define NEXP 8
#define BM 256
#define BN 256
#define BK 64
#define CAPROWS (NTOK * 2 + NEXP * BM) /* 10240 padded rows worst case */
#define MAXTILES (CAPROWS / BM)        /* 40 */

typedef float f32x4_t __attribute__((ext_vector_type(4)));
typedef short bf16x8_t __attribute__((ext_vector_type(8)));
using bf16_t = __hip_bfloat16;

#define S_BARRIER()                         \
  do {                                      \
    __builtin_amdgcn_sched_barrier(0);      \
    __builtin_amdgcn_s_barrier();           \
    __builtin_amdgcn_sched_barrier(0);      \
  } while (0)
#define WAIT_VMCNT(n)                                       \
  do {                                                      \
    asm volatile("s_waitcnt vmcnt(" #n ")" ::: "memory");   \
    __builtin_amdgcn_sched_barrier(0);                      \
  } while (0)

__device__ __forceinline__ void gll16(const void* g, void* l) {
  __builtin_amdgcn_global_load_lds(
      (__attribute__((address_space(1))) void*)(void*)g,
      (__attribute__((address_space(3))) void*)l, 16, 0, 0);
}

// ---------------- gate: logits + softmax + top2 (all fp32, exact) -----------
__global__ __launch_bounds__(256) void gate_kernel(
    const float* __restrict__ x, const float* __restrict__ gw,
    const float* __restrict__ gb, int* __restrict__ top_idx,
    float* __restrict__ top_val, int* __restrict__ counts) {
  int n = blockIdx.x * 4 + (threadIdx.x >> 6);
  int l = threadIdx.x & 63;
  const float4* xv = (const float4*)(x + (size_t)n * DDIM);
  float4 xs[4];
#pragma unroll
  for (int j = 0; j < 4; ++j) xs[j] = xv[l + 64 * j];
  float part[NEXP];
#pragma unroll
  for (int e = 0; e < NEXP; ++e) {
    const float4* wv = (const float4*)(gw + (size_t)e * DDIM);
    float s = 0.f;
#pragma unroll
    for (int j = 0; j < 4; ++j) {
      float4 w4 = wv[l + 64 * j];
      s += xs[j].x * w4.x + xs[j].y * w4.y + xs[j].z * w4.z + xs[j].w * w4.w;
    }
    part[e] = s;
  }
#pragma unroll
  for (int off = 32; off > 0; off >>= 1)
#pragma unroll
    for (int e = 0; e < NEXP; ++e) part[e] += __shfl_xor(part[e], off, 64);

  float m = -1e30f;
#pragma unroll
  for (int e = 0; e < NEXP; ++e) { part[e] += gb[e]; m = fmaxf(m, part[e]); }
  float ssum = 0.f;
#pragma unroll
  for (int e = 0; e < NEXP; ++e) { part[e] = expf(part[e] - m); ssum += part[e]; }
  int i0 = 0; float v0 = part[0];
#pragma unroll
  for (int e = 1; e < NEXP; ++e) if (part[e] > v0) { v0 = part[e]; i0 = e; }
  int i1 = -1; float v1 = -1e30f;
#pragma unroll
  for (int e = 0; e < NEXP; ++e) if (e != i0 && part[e] > v1) { v1 = part[e]; i1 = e; }
  if (l == 0) {
    float inv = 1.f / ssum;
    top_idx[n * 2] = i0; top_idx[n * 2 + 1] = i1;
    top_val[n * 2] = v0 * inv; top_val[n * 2 + 1] = v1 * inv;
    atomicAdd(&counts[i0], 1); atomicAdd(&counts[i1], 1);
  }
}

// ---------------- plan: padded prefix offsets + static tile table -----------
__global__ void plan_kernel(const int* __restrict__ counts, int* __restrict__ offs,
                            int* __restrict__ tile_e, int* __restrict__ tile_r) {
  if (threadIdx.x != 0 || blockIdx.x != 0) return;
  int off = 0, t = 0;
  for (int e = 0; e < NEXP; ++e) {
    offs[e] = off;
    int padded = ((counts[e] + BM - 1) / BM) * BM;
    for (int r = 0; r < padded; r += BM) { tile_e[t] = e; tile_r[t] = off + r; ++t; }
    off += padded;
  }
  offs[NEXP] = off;
  for (; t < MAXTILES; ++t) { tile_e[t] = -1; tile_r[t] = 0; }
}

// ---------------- gather: token rows -> per-expert bf16 blocks --------------
__global__ __launch_bounds__(128) void gather_kernel(
    const float* __restrict__ x, const int* __restrict__ top_idx,
    const int* __restrict__ offs, int* __restrict__ cursors,
    int* __restrict__ slot_for, bf16_t* __restrict__ Xg) {
  int a = blockIdx.x;
  __shared__ int s_slot;
  if (threadIdx.x == 0) {
    int e = top_idx[a];
    int pos = atomicAdd(&cursors[e], 1);
    int slot = offs[e] + pos;
    slot_for[a] = slot;
    s_slot = slot;
  }
  __syncthreads();
  int slot = s_slot;
  int n = a >> 1;
  const float4* xv = (const float4*)(x + (size_t)n * DDIM);
  float4 a0 = xv[threadIdx.x * 2], a1 = xv[threadIdx.x * 2 + 1];
  __align__(16) bf16_t tmp[8] = {
      __float2bfloat16(a0.x), __float2bfloat16(a0.y),
      __float2bfloat16(a0.z), __float2bfloat16(a0.w),
      __float2bfloat16(a1.x), __float2bfloat16(a1.y),
      __float2bfloat16(a1.z), __float2bfloat16(a1.w)};
  *(uint4*)(Xg + (size_t)slot * DDIM + threadIdx.x * 8) = *(const uint4*)tmp;
}

// ---------------- transpose-convert fp32 [E][R][C] -> bf16 [E][C][R] --------
__global__ __launch_bounds__(256) void convT_kernel(
    const float* __restrict__ src, bf16_t* __restrict__ dst, int R, int C) {
  __shared__ float tile[64][65];
  int e = blockIdx.z;
  int c0 = blockIdx.x * 64, r0 = blockIdx.y * 64;
  const float* s = src + ((size_t)e * R + r0) * C + c0;
  int tc = threadIdx.x & 63, tr = threadIdx.x >> 6;
#pragma unroll
  for (int p = 0; p < 16; ++p) {
    int r = tr + p * 4;
    tile[r][tc] = s[(size_t)r * C + tc];
  }
  __syncthreads();
  bf16_t* dcol = dst + ((size_t)e * C + c0) * R + r0;
  int t = threadIdx.x;
#pragma unroll
  for (int it = 0; it < 2; ++it) {
    int c = (t >> 3) + it * 32;
    int r8 = (t & 7) * 8;
    __align__(16) bf16_t v[8];
#pragma unroll
    for (int j = 0; j < 8; ++j) v[j] = __float2bfloat16(tile[r8 + j][c]);
    *(uint4*)(dcol + (size_t)c * R + r8) = *(const uint4*)v;
  }
}

// ---------------- 256x256 MFMA GEMM, deep-pipelined (T2+T3+T4+T5) -----------
// C = A[M][K] @ Bt[N][K]^T per expert-tile. 512 thr = 8 waves (2M x 4N);
// per-wave 128x64 out; BK=64; 2 LDS dbufs, XOR-swizzled via pre-swizzled
// global source (linear gll16 dest) + swizzled ds_read.
// K-tile t (dbuf d=t&1): ph0 reads ALL A-frags (ak0,ak1) + bv0 -> A region
// dead after ph0, so BOTH A and B stage tile t+2 (A at ph1/ph2, B at ph3).
// vmcnt(8) at ph3 = keep tile t+2's 8 loads in flight, drain t+1's. Compiler
// emits minimal counted lgkmcnt for ds_read->MFMA (no inline-asm reads).
template <int KTOT, int NTOT, int WHICH>
__global__ __launch_bounds__(512, 2) void gemm8_kernel(
    const bf16_t* __restrict__ A, const bf16_t* __restrict__ Bt,
    const float* __restrict__ bias, void* __restrict__ Cout,
    const int* __restrict__ tile_e, const int* __restrict__ tile_r) {
  constexpr int NCOL = NTOT / BN;
  // bijective XCD-chunked swizzle (m204)
  int nwg = gridDim.x;
  int bid = blockIdx.x;
  int q = nwg >> 3, rr = nwg & 7;
  int xcd = bid & 7, pos = bid >> 3;
  int swz = (xcd < rr ? xcd * (q + 1) : rr * (q + 1) + (xcd - rr) * q) + pos;
  int ty = swz / NCOL, tx = swz % NCOL;

  int e = tile_e[ty];
  if (e < 0) return;
  int row0 = tile_r[ty];
  int n0 = tx * BN;

  __shared__ char smem[131072];
  int tid = threadIdx.x;
  int w = tid >> 6, l = tid & 63;
  int wm = w >> 2, wn = w & 3;
  int lrow = l & 15, lk = l >> 4;

  const bf16_t* Ab = A + (size_t)row0 * KTOT;
  const bf16_t* Bb = Bt + ((size_t)e * NTOT + n0) * KTOT;

  int sidx0 = tid, sidx1 = 512 + tid;
  int sr0 = sidx0 >> 3, sc0 = (sidx0 & 7) ^ (sr0 & 7);
  int sr1 = sidx1 >> 3, sc1 = (sidx1 & 7) ^ (sr1 & 7);

  auto stageA = [&](int kt, int h, int d) {
    char* lb = smem + d * 32768 + h * 16384;
    const bf16_t* g = Ab + (size_t)(h * 128) * KTOT + kt * BK;
    gll16(g + (size_t)sr0 * KTOT + sc0 * 8, lb + sidx0 * 16);
    gll16(g + (size_t)sr1 * KTOT + sc1 * 8, lb + sidx1 * 16);
  };
  auto stageB = [&](int kt, int h, int d) {
    char* lb = smem + 65536 + d * 32768 + h * 16384;
    const bf16_t* g = Bb + (size_t)(h * 128) * KTOT + kt * BK;
    gll16(g + (size_t)sr0 * KTOT + sc0 * 8, lb + sidx0 * 16);
    gll16(g + (size_t)sr1 * KTOT + sc1 * 8, lb + sidx1 * 16);
  };

  int abase = (wm * 128 + lrow) * 128;
  int bbase = (wn * 64 + lrow) * 128;
  int p0 = ((lk) ^ (lrow & 7)) * 16;
  int p1 = ((4 + lk) ^ (lrow & 7)) * 16;

  f32x4_t acc[8][4];
#pragma unroll
  for (int m = 0; m < 8; ++m)
#pragma unroll
    for (int n = 0; n < 4; ++n) acc[m][n] = (f32x4_t){0.f, 0.f, 0.f, 0.f};

  const int NKT = KTOT / BK;

  // prologue: tiles 0 and 1 fully staged; wait tile 0 landed (8 of 16).
  stageA(0, 0, 0); stageA(0, 1, 0);
  stageB(0, 0, 0); stageB(0, 1, 0);
  stageA(1, 0, 1); stageA(1, 1, 1);
  stageB(1, 0, 1); stageB(1, 1, 1);
  WAIT_VMCNT(8);
  S_BARRIER();

  for (int t = 0; t < NKT; ++t) {
    int d = t & 1;
    const char* Ad = smem + d * 32768;
    const char* Bd = smem + 65536 + d * 32768;
    bf16x8_t ak0[8], ak1[8], bv0[4], bv1[4];
    bool pre = (t + 2 < NKT);
    // ---- ph0: read ak0, bv0, ak1 (A region dead afterwards) ----
#pragma unroll
    for (int m = 0; m < 8; ++m)
      ak0[m] = *(const bf16x8_t*)(Ad + abase + m * 2048 + p0);
#pragma unroll
    for (int n = 0; n < 4; ++n)
      bv0[n] = *(const bf16x8_t*)(Bd + bbase + n * 2048 + p0);
#pragma unroll
    for (int m = 0; m < 8; ++m)
      ak1[m] = *(const bf16x8_t*)(Ad + abase + m * 2048 + p1);
    S_BARRIER();
    __builtin_amdgcn_s_setprio(1);
#pragma unroll
    for (int m = 0; m < 4; ++m)
#pragma unroll
      for (int n = 0; n < 4; ++n)
        acc[m][n] = __builtin_amdgcn_mfma_f32_16x16x32_bf16(ak0[m], bv0[n], acc[m][n], 0, 0, 0);
    __builtin_amdgcn_s_setprio(0);
    S_BARRIER();
    // ---- ph1: stage A(t+2) h0 into dead A region ----
    if (pre) stageA(t + 2, 0, d);
    S_BARRIER();
    __builtin_amdgcn_s_setprio(1);
#pragma unroll
    for (int m = 4; m < 8; ++m)
#pragma unroll
      for (int n = 0; n < 4; ++n)
        acc[m][n] = __builtin_amdgcn_mfma_f32_16x16x32_bf16(ak0[m], bv0[n], acc[m][n], 0, 0, 0);
    __builtin_amdgcn_s_setprio(0);
    S_BARRIER();
    // ---- ph2: read bv1; stage A(t+2) h1 ----
#pragma unroll
    for (int n = 0; n < 4; ++n)
      bv1[n] = *(const bf16x8_t*)(Bd + bbase + n * 2048 + p1);
    if (pre) stageA(t + 2, 1, d);
    S_BARRIER();
    __builtin_amdgcn_s_setprio(1);
#pragma unroll
    for (int m = 0; m < 4; ++m)
#pragma unroll
      for (int n = 0; n < 4; ++n)
        acc[m][n] = __builtin_amdgcn_mfma_f32_16x16x32_bf16(ak1[m], bv1[n], acc[m][n], 0, 0, 0);
    __builtin_amdgcn_s_setprio(0);
    S_BARRIER();
    // ---- ph3: stage B(t+2); counted drain (t+1 landed, t+2 in flight) ----
    if (pre) {
      stageB(t + 2, 0, d);
      stageB(t + 2, 1, d);
      WAIT_VMCNT(8);
    } else {
      WAIT_VMCNT(0);
    }
    S_BARRIER();
    __builtin_amdgcn_s_setprio(1);
#pragma unroll
    for (int m = 4; m < 8; ++m)
#pragma unroll
      for (int n = 0; n < 4; ++n)
        acc[m][n] = __builtin_amdgcn_mfma_f32_16x16x32_bf16(ak1[m], bv1[n], acc[m][n], 0, 0, 0);
    __builtin_amdgcn_s_setprio(0);
    S_BARRIER();
  }

  // ---- epilogue via LDS: scattered 2B/4B stores -> coalesced 16B runs ----
  // acc(m,n,i) -> row = wm*128+m*16+lk*4+i, col = wn*64+n*16+lrow [m89]
  if (WHICH == 1) {
    // bf16 out: stage full 256x256 bf16 tile (128KB) in LDS.
#pragma unroll
    for (int n = 0; n < 4; ++n) {
      int col = wn * 64 + n * 16 + lrow;
      float bb = bias[e * NTOT + n0 + col];
#pragma unroll
      for (int m = 0; m < 8; ++m) {
        int rb = wm * 128 + m * 16 + lk * 4;
#pragma unroll
        for (int i = 0; i < 4; ++i) {
          float v = acc[m][n][i] + bb;
          v = v > 0.f ? v : 0.f;
          *(bf16_t*)(smem + (size_t)(rb + i) * 512 + col * 2) = __float2bfloat16(v);
        }
      }
    }
    S_BARRIER();
#pragma unroll
    for (int p = 0; p < 16; ++p) {
      int idx = p * 512 + tid;
      int row = idx >> 5, ch = idx & 31;
      uint4 v = *(const uint4*)(smem + (size_t)row * 512 + ch * 16);
      *(uint4*)((char*)Cout + ((size_t)(row0 + row) * NTOT + n0) * 2 + ch * 16) = v;
    }
  } else {
    // f32 out: two half-tiles of 128 rows x 256 cols f32 (128KB each).
#pragma unroll
    for (int h = 0; h < 2; ++h) {
      if (h) S_BARRIER();
      if (wm == h) {
#pragma unroll
        for (int n = 0; n < 4; ++n) {
          int col = wn * 64 + n * 16 + lrow;
          float bb = bias[e * NTOT + n0 + col];
#pragma unroll
          for (int m = 0; m < 8; ++m) {
            int rb = m * 16 + lk * 4;
#pragma unroll
            for (int i = 0; i < 4; ++i)
              *(float*)(smem + (size_t)(rb + i) * 1024 + col * 4) = acc[m][n][i] + bb;
          }
        }
      }
      S_BARRIER();
#pragma unroll
      for (int p = 0; p < 16; ++p) {
        int idx = p * 512 + tid;
        int row = idx >> 6, ch = idx & 63;
        uint4 v = *(const uint4*)(smem + (size_t)row * 1024 + ch * 16);
        *(uint4*)((char*)Cout + ((size_t)(row0 + h * 128 + row) * NTOT + n0) * 4 + ch * 16) = v;
      }
    }
  }
}

// ---------------- combine: out[n] = g0*Y[s0] + g1*Y[s1] ---------------------
__global__ __launch_bounds__(256) void combine_kernel(
    const float* __restrict__ Y, const int* __restrict__ slot_for,
    const float* __restrict__ top_val, float* __restrict__ out) {
  int n = blockIdx.x;
  int s0 = slot_for[n * 2], s1 = slot_for[n * 2 + 1];
  float v0 = top_val[n * 2], v1 = top_val[n * 2 + 1];
  int t = threadIdx.x;
  float4 a = ((const float4*)(Y + (size_t)s0 * ODIM))[t];
  float4 b = ((const float4*)(Y + (size_t)s1 * ODIM))[t];
  float4 r;
  r.x = v0 * a.x + v1 * b.x;
  r.y = v0 * a.y + v1 * b.y;
  r.z = v0 * a.z + v1 * b.z;
  r.w = v0 * a.w + v1 * b.w;
  ((float4*)(out + (size_t)n * ODIM))[t] = r;
}

__global__ void zero_meta_kernel(int* p) {
  if (threadIdx.x < 16) p[threadIdx.x] = 0;
}

extern "C" void kernel_launch(void* const* d_in, const int* in_sizes, int n_in,
                              void* d_out, int out_size, void* d_ws, size_t ws_size,
                              hipStream_t stream) {
  const float* x  = (const float*)d_in[0];
  const float* gw = (const float*)d_in[1];
  const float* gb = (const float*)d_in[2];
  const float* w1 = (const float*)d_in[3];
  const float* b1 = (const float*)d_in[4];
  const float* w2 = (const float*)d_in[5];
  const float* b2 = (const float*)d_in[6];
  float* out = (float*)d_out;

  char* ws = (char*)d_ws;
  size_t off = 0;
  auto alloc = [&](size_t bytes) {
    void* p = ws + off;
    off = (off + bytes + 255) & ~(size_t)255;
    return p;
  };
  bf16_t* w1T = (bf16_t*)alloc((size_t)NEXP * HDIM * DDIM * 2);  // 67.1 MB
  bf16_t* w2T = (bf16_t*)alloc((size_t)NEXP * ODIM * HDIM * 2);  // 67.1 MB
  bf16_t* Xg  = (bf16_t*)alloc((size_t)CAPROWS * DDIM * 2);      // 21.0 MB
  bf16_t* Hb  = (bf16_t*)alloc((size_t)CAPROWS * HDIM * 2);      // 83.9 MB
  int* counts  = (int*)alloc(64);  // counts[8] + cursors[8]
  int* cursors = counts + 8;
  int* offs    = (int*)alloc(64);
  int* tile_e  = (int*)alloc(MAXTILES * 4);
  int* tile_r  = (int*)alloc(MAXTILES * 4);
  int* top_idx = (int*)alloc((size_t)NTOK * 2 * 4);
  float* top_val = (float*)alloc((size_t)NTOK * 2 * 4);
  int* slot_for = (int*)alloc((size_t)NTOK * 2 * 4);
  // GEMM2 output overlays w1T (dead after GEMM1): 41.9 MB <= 67.1 MB
  float* Yb = (float*)w1T;

  hipLaunchKernelGGL(zero_meta_kernel, dim3(1), dim3(64), 0, stream, counts);
  hipLaunchKernelGGL(convT_kernel, dim3(HDIM / 64, DDIM / 64, NEXP), dim3(256), 0,
                     stream, w1, w1T, DDIM, HDIM);
  hipLaunchKernelGGL(convT_kernel, dim3(ODIM / 64, HDIM / 64, NEXP), dim3(256), 0,
                     stream, w2, w2T, HDIM, ODIM);
  hipLaunchKernelGGL(gate_kernel, dim3(NTOK / 4), dim3(256), 0, stream,
                     x, gw, gb, top_idx, top_val, counts);
  hipLaunchKernelGGL(plan_kernel, dim3(1), dim3(1), 0, stream,
                     counts, offs, tile_e, tile_r);
  hipLaunchKernelGGL(gather_kernel, dim3(NTOK * 2), dim3(128), 0, stream,
                     x, top_idx, offs, cursors, slot_for, Xg);
  hipLaunchKernelGGL((gemm8_kernel<DDIM, HDIM, 1>),
                     dim3((HDIM / BN) * MAXTILES), dim3(512), 0, stream,
                     Xg, w1T, b1, Hb, tile_e, tile_r);
  hipLaunchKernelGGL((gemm8_kernel<HDIM, ODIM, 2>),
                     dim3((ODIM / BN) * MAXTILES), dim3(512), 0, stream,
                     Hb, w2T, b2, Yb, tile_e, tile_r);
  hipLaunchKernelGGL(combine_kernel, dim3(NTOK), dim3(256), 0, stream,
                     Yb, slot_for, top_val, out);
}